// Round 20
// baseline (193.275 us; speedup 1.0000x reference)
//
#include <hip/hip_runtime.h>
#include <hip/hip_fp16.h>
#include <cstdint>

typedef int v4i  __attribute__((ext_vector_type(4)));
typedef int v16i __attribute__((ext_vector_type(16)));

#define AS1C(p) ((const __attribute__((address_space(1))) void*)(p))
#define AS3(p)  ((__attribute__((address_space(3))) void*)(p))

// ---------------------------------------------------------------------------
// Fused per-row symmetric int8 quantization (r19 version: 64 contiguous
// bytes/thread, one 16-B store).
// ---------------------------------------------------------------------------
__global__ __launch_bounds__(256) void quant_fused(const float* __restrict__ X,
                                                   const float* __restrict__ W,
                                                   int8_t* __restrict__ Xq,
                                                   int8_t* __restrict__ Wq,
                                                   float* __restrict__ a_scale,
                                                   float* __restrict__ w_scale) {
    const int row = blockIdx.x;
    const float* src;
    int8_t* dst;
    float* scp;
    if (row < 8192) {
        src = X + (size_t)row * 4096;  dst = Xq + (size_t)row * 4096;  scp = a_scale + row;
    } else {
        const int r = row - 8192;
        src = W + (size_t)r * 4096;    dst = Wq + (size_t)r * 4096;    scp = w_scale + r;
    }
    const float4* xv = (const float4*)src;
    const int tid = threadIdx.x;

    float4 v[4];
#pragma unroll
    for (int j = 0; j < 4; ++j) v[j] = xv[tid * 4 + j];

    float m = 0.0f;
#pragma unroll
    for (int j = 0; j < 4; ++j) {
        m = fmaxf(m, fmaxf(fmaxf(fabsf(v[j].x), fabsf(v[j].y)),
                           fmaxf(fabsf(v[j].z), fabsf(v[j].w))));
    }
    for (int off = 32; off > 0; off >>= 1)
        m = fmaxf(m, __shfl_xor(m, off, 64));

    __shared__ float wmax[4];
    __shared__ float s_sc;
    const int lane = tid & 63;
    const int wv = tid >> 6;
    if (lane == 0) wmax[wv] = m;
    __syncthreads();
    if (tid == 0) {
        float mm = fmaxf(fmaxf(wmax[0], wmax[1]), fmaxf(wmax[2], wmax[3]));
        float sc = mm / 127.0f;
        *scp = sc;
        s_sc = sc;
    }
    __syncthreads();
    const float sc = s_sc;

    v4i qw;
#pragma unroll
    for (int j = 0; j < 4; ++j) {
        const int b0 = (int)(unsigned char)(signed char)(int)rintf(v[j].x / sc);
        const int b1 = (int)(unsigned char)(signed char)(int)rintf(v[j].y / sc);
        const int b2 = (int)(unsigned char)(signed char)(int)rintf(v[j].z / sc);
        const int b3 = (int)(signed char)(int)rintf(v[j].w / sc);
        qw[j] = b0 | (b1 << 8) | (b2 << 16) | (b3 << 24);
    }
    *(v4i*)(dst + (size_t)tid * 16) = qw;
}

// ---------------------------------------------------------------------------
// int8 GEMM — r7 skeleton (ring, role split, setprio, fences, staging all
// identical) with ONE variable changed: MFMA shape 16x16x64 -> 32x32x32
// (µbench 4404 vs 3944 TOPS: per-K-tile MFMA 1306 -> ~1170 cyc/CU, and
// instruction count halves 32 -> 16). LDS traffic is shape-invariant
// (same 12 ds_read_b128/K-tile/wave). Per-wave 128x64 = 4x2 grid of
// 32x32 tiles, acc = 8 x v16i = 128 regs (AGPR half, as in r7).
// A frag: row = lane&31, k-chunk = (lane>>5)*16 B (scale-up of the
// verified 16x16x64 mapping); swizzle XOR term (row>>1)&3 is invariant
// across 32-row strides -> folded into per-lane chunk constants.
// C/D: col = lane&31, row = (reg&3)+8*(reg>>2)+4*(lane>>5) [m74/m101,
// dtype-independent per m121/m127].
// ---------------------------------------------------------------------------
__global__ __launch_bounds__(512, 2) void gemm_i8(const int8_t* __restrict__ Aq,
                                                  const int8_t* __restrict__ Bq,
                                                  const float* __restrict__ a_scale,
                                                  const float* __restrict__ w_scale,
                                                  float* __restrict__ out) {
    extern __shared__ __align__(16) int8_t smem[];  // 4 x (A 16K | B 16K)

    const int K = 4096;
    const int bid = blockIdx.x;
    const int wg  = (bid & 7) * 64 + (bid >> 3);  // bijective: 512 = 8 x 64
    const int n0 = (wg & 15) * 256;
    const int m0 = (wg >> 4) * 256;

    const int tid  = threadIdx.x;
    const int lane = tid & 63;
    const int wid  = tid >> 6;
    const int wm   = wid >> 2;   // 0..1 -> M offset wm*128
    const int wn   = wid & 3;    // 0..3 -> N offset wn*64

    // 32x32 fragment addressing
    const int rsel32 = lane & 31;
    const int hi     = lane >> 5;                 // k-half selector
    const int arow   = wm * 128 + rsel32;         // LDS A row base (rb adds 32)
    const int brow   = wn * 64  + rsel32;         // LDS B row base (cb adds 32)
    const int swzA   = (arow >> 1) & 3;           // invariant across rb (32-row stride)
    const int swzB   = (brow >> 1) & 3;           // invariant across cb
    const int abase32 = arow * 64;
    const int bbase32 = 16384 + brow * 64;
    const int chA0 = ((0 + hi) ^ swzA) << 4;      // ks=0 chunk (swizzled)
    const int chA1 = ((2 + hi) ^ swzA) << 4;      // ks=1 chunk
    const int chB0 = ((0 + hi) ^ swzB) << 4;
    const int chB1 = ((2 + hi) ^ swzB) << 4;

    // staging: 512 thr x 16 B = 128 rows/issue; pre-swizzled global source
    const int strow = tid >> 2;
    const int stswz = ((strow >> 1) & 3) << 4;
    const int stcol = ((tid & 3) << 4) ^ stswz;
    const int8_t* gA = Aq + (size_t)(m0 + strow) * K + stcol;
    const int8_t* gB = Bq + (size_t)(n0 + strow) * K + stcol;
    const size_t rstep = (size_t)128 * K;
    const int ldsst = wid * 1024;  // + lane*16 by HW

    v16i acc[8] = {};               // acc[rb*2+cb], 128 regs -> AGPR half
    v4i aFa[8], aFb[8], bFa[4], bFb[4];  // frag idx: A[2*rb+ks], B[cb*2+ks]

#define STAGE(buf, kt) do {                                                          \
    int8_t* _d = smem + (buf) * 32768;                                               \
    const int8_t* _a = gA + (size_t)(kt) * 64;                                       \
    const int8_t* _b = gB + (size_t)(kt) * 64;                                       \
    __builtin_amdgcn_global_load_lds(AS1C(_a),         AS3(_d + ldsst),         16, 0, 0); \
    __builtin_amdgcn_global_load_lds(AS1C(_a + rstep), AS3(_d + 8192  + ldsst), 16, 0, 0); \
    __builtin_amdgcn_global_load_lds(AS1C(_b),         AS3(_d + 16384 + ldsst), 16, 0, 0); \
    __builtin_amdgcn_global_load_lds(AS1C(_b + rstep), AS3(_d + 24576 + ldsst), 16, 0, 0); \
  } while (0)

#define READS(g, NA, NB, gsrc, goff) do {                                            \
    NA[2*(g)]     = *(const v4i*)(bufN + abase32 + (g) * 2048 + chA0);               \
    NA[2*(g) + 1] = *(const v4i*)(bufN + abase32 + (g) * 2048 + chA1);               \
    NB[(g)]       = *(const v4i*)(bufN + bbase32 + ((g) >> 1) * 2048                 \
                                  + (((g) & 1) ? chB1 : chB0));                      \
    __builtin_amdgcn_global_load_lds(AS1C(gsrc), AS3(pD + (goff) + ldsst), 16, 0, 0);\
  } while (0)

    // group g = row-block rb: 4 MFMAs (2 cb x 2 ks), ks chained into same acc
#define MFMAS(g, CA, CB) do {                                                        \
    __builtin_amdgcn_s_setprio(1);                                                   \
    acc[2*(g)]   = __builtin_amdgcn_mfma_i32_32x32x32_i8(CA[2*(g)],   CB[0],         \
                                                         acc[2*(g)],   0, 0, 0);    \
    acc[2*(g)]   = __builtin_amdgcn_mfma_i32_32x32x32_i8(CA[2*(g)+1], CB[1],         \
                                                         acc[2*(g)],   0, 0, 0);    \
    acc[2*(g)+1] = __builtin_amdgcn_mfma_i32_32x32x32_i8(CA[2*(g)],   CB[2],         \
                                                         acc[2*(g)+1], 0, 0, 0);    \
    acc[2*(g)+1] = __builtin_amdgcn_mfma_i32_32x32x32_i8(CA[2*(g)+1], CB[3],         \
                                                         acc[2*(g)+1], 0, 0, 0);    \
    __builtin_amdgcn_s_setprio(0);                                                   \
  } while (0)

#define GROUP_RW(g, CA, CB, NA, NB, gsrc, goff)  do {                                \
    READS(g, NA, NB, gsrc, goff);                                                    \
    __builtin_amdgcn_sched_barrier(0);                                               \
    MFMAS(g, CA, CB);                                                                \
    __builtin_amdgcn_sched_barrier(0);                                               \
  } while (0)

#define GROUP_WR(g, CA, CB, NA, NB, gsrc, goff)  do {                                \
    MFMAS(g, CA, CB);                                                                \
    __builtin_amdgcn_sched_barrier(0);                                               \
    READS(g, NA, NB, gsrc, goff);                                                    \
    __builtin_amdgcn_sched_barrier(0);                                               \
  } while (0)

#define KSTEP(G, u, CA, CB, NA, NB, kt4) do {                                        \
    const int kt  = (kt4) + (u);                                                     \
    const int8_t* bufN = smem + (((u) + 1) & 3) * 32768;                             \
    int8_t* pD = smem + (((u) + 3) & 3) * 32768;                                     \
    const int ktp = (kt + 3 < 64) ? (kt + 3) : 63;                                   \
    const int8_t* _a = gA + (size_t)ktp * 64;                                        \
    const int8_t* _b = gB + (size_t)ktp * 64;                                        \
    asm volatile("s_waitcnt vmcnt(4)" ::: "memory");                                 \
    __builtin_amdgcn_s_barrier();                                                    \
    __builtin_amdgcn_sched_barrier(0);                                               \
    G(0, CA, CB, NA, NB, _a,         0);                                             \
    G(1, CA, CB, NA, NB, _a + rstep, 8192);                                          \
    G(2, CA, CB, NA, NB, _b,         16384);                                         \
    G(3, CA, CB, NA, NB, _b + rstep, 24576);                                         \
  } while (0)

    // ---- prologue: stage tiles 0..2; retire tile 0; load its fragments
    STAGE(0, 0); STAGE(1, 1); STAGE(2, 2);
    asm volatile("s_waitcnt vmcnt(8)" ::: "memory");
    __builtin_amdgcn_s_barrier();
#pragma unroll
    for (int g = 0; g < 4; ++g) {
        aFa[2*g]     = *(const v4i*)(smem + abase32 + g * 2048 + chA0);
        aFa[2*g + 1] = *(const v4i*)(smem + abase32 + g * 2048 + chA1);
        bFa[g]       = *(const v4i*)(smem + bbase32 + (g >> 1) * 2048
                                     + ((g & 1) ? chB1 : chB0));
    }

    if (wid < 4) {  // lead waves: one per SIMD
        for (int kt4 = 0; kt4 < 64; kt4 += 4) {
            KSTEP(GROUP_RW, 0, aFa, bFa, aFb, bFb, kt4);
            KSTEP(GROUP_RW, 1, aFb, bFb, aFa, bFa, kt4);
            KSTEP(GROUP_RW, 2, aFa, bFa, aFb, bFb, kt4);
            KSTEP(GROUP_RW, 3, aFb, bFb, aFa, bFa, kt4);
        }
    } else {        // lag waves: SIMD siblings, anti-phased by construction
        for (int kt4 = 0; kt4 < 64; kt4 += 4) {
            KSTEP(GROUP_WR, 0, aFa, bFa, aFb, bFb, kt4);
            KSTEP(GROUP_WR, 1, aFb, bFb, aFa, bFa, kt4);
            KSTEP(GROUP_WR, 2, aFa, bFa, aFb, bFb, kt4);
            KSTEP(GROUP_WR, 3, aFb, bFb, aFa, bFa, kt4);
        }
    }

    // epilogue: 32x32 C/D layout — col = lane&31, row = (reg&3)+8*(reg>>2)+4*hi
#pragma unroll
    for (int rb = 0; rb < 4; ++rb) {
        const int tbase = m0 + wm * 128 + rb * 32;
        float as[16];
#pragma unroll
        for (int q = 0; q < 4; ++q)
#pragma unroll
            for (int j = 0; j < 4; ++j)
                as[q * 4 + j] = a_scale[tbase + 8 * q + 4 * hi + j];
#pragma unroll
        for (int cb = 0; cb < 2; ++cb) {
            const int o = n0 + wn * 64 + cb * 32 + rsel32;
            const float wsc = w_scale[o];
            const v16i a16 = acc[rb * 2 + cb];
#pragma unroll
            for (int reg = 0; reg < 16; ++reg) {
                const int row = tbase + (reg & 3) + 8 * (reg >> 2) + 4 * hi;
                float v = (float)a16[reg] * as[reg] * wsc;
                out[(size_t)row * 4096 + o] = __half2float(__float2half_rn(v));
            }
        }
    }
#undef KSTEP
#undef GROUP_RW
#undef GROUP_WR
#undef MFMAS
#undef READS
#undef STAGE
}

extern "C" void kernel_launch(void* const* d_in, const int* in_sizes, int n_in,
                              void* d_out, int out_size, void* d_ws, size_t ws_size,
                              hipStream_t stream) {
    const float* input_act = (const float*)d_in[0];  // [4,2048,4096] = [8192,4096]
    const float* weight    = (const float*)d_in[1];  // [4096,4096]
    float* out = (float*)d_out;

    const int K = 4096, O = 4096, T = 8192;

    int8_t* x_q = (int8_t*)d_ws;
    int8_t* w_q = x_q + (size_t)T * K;
    float* a_scale = (float*)(w_q + (size_t)O * K);
    float* w_scale = a_scale + T;

    static bool attr_done = false;
    if (!attr_done) {
        hipFuncSetAttribute(reinterpret_cast<const void*>(gemm_i8),
                            hipFuncAttributeMaxDynamicSharedMemorySize, 131072);
        attr_done = true;
    }

    quant_fused<<<T + O, 256, 0, stream>>>(input_act, weight, x_q, w_q,
                                           a_scale, w_scale);

    dim3 grid(512);  // (8192/256) x (4096/256), XCD-swizzled in-kernel
    gemm_i8<<<grid, 512, 131072, stream>>>(x_q, w_q, a_scale, w_scale, out);
}

// Round 21
// 177.218 us; speedup vs baseline: 1.0906x; 1.0906x over previous
//
#include <hip/hip_runtime.h>
#include <hip/hip_fp16.h>
#include <cstdint>

typedef int v4i __attribute__((ext_vector_type(4)));

#define AS1C(p) ((const __attribute__((address_space(1))) void*)(p))
#define AS3(p)  ((__attribute__((address_space(3))) void*)(p))

// ---------------------------------------------------------------------------
// Fused per-row symmetric int8 quantization. Single pass, row in registers;
// each thread owns 64 contiguous bytes -> one 16-B store (r19 version).
// ---------------------------------------------------------------------------
__global__ __launch_bounds__(256) void quant_fused(const float* __restrict__ X,
                                                   const float* __restrict__ W,
                                                   int8_t* __restrict__ Xq,
                                                   int8_t* __restrict__ Wq,
                                                   float* __restrict__ a_scale,
                                                   float* __restrict__ w_scale) {
    const int row = blockIdx.x;
    const float* src;
    int8_t* dst;
    float* scp;
    if (row < 8192) {
        src = X + (size_t)row * 4096;  dst = Xq + (size_t)row * 4096;  scp = a_scale + row;
    } else {
        const int r = row - 8192;
        src = W + (size_t)r * 4096;    dst = Wq + (size_t)r * 4096;    scp = w_scale + r;
    }
    const float4* xv = (const float4*)src;
    const int tid = threadIdx.x;

    float4 v[4];
#pragma unroll
    for (int j = 0; j < 4; ++j) v[j] = xv[tid * 4 + j];

    float m = 0.0f;
#pragma unroll
    for (int j = 0; j < 4; ++j) {
        m = fmaxf(m, fmaxf(fmaxf(fabsf(v[j].x), fabsf(v[j].y)),
                           fmaxf(fabsf(v[j].z), fabsf(v[j].w))));
    }
    for (int off = 32; off > 0; off >>= 1)
        m = fmaxf(m, __shfl_xor(m, off, 64));

    __shared__ float wmax[4];
    __shared__ float s_sc;
    const int lane = tid & 63;
    const int wv = tid >> 6;
    if (lane == 0) wmax[wv] = m;
    __syncthreads();
    if (tid == 0) {
        float mm = fmaxf(fmaxf(wmax[0], wmax[1]), fmaxf(wmax[2], wmax[3]));
        float sc = mm / 127.0f;
        *scp = sc;
        s_sc = sc;
    }
    __syncthreads();
    const float sc = s_sc;

    v4i qw;
#pragma unroll
    for (int j = 0; j < 4; ++j) {
        const int b0 = (int)(unsigned char)(signed char)(int)rintf(v[j].x / sc);
        const int b1 = (int)(unsigned char)(signed char)(int)rintf(v[j].y / sc);
        const int b2 = (int)(unsigned char)(signed char)(int)rintf(v[j].z / sc);
        const int b3 = (int)(signed char)(int)rintf(v[j].w / sc);
        qw[j] = b0 | (b1 << 8) | (b2 << 16) | (b3 << 24);
    }
    *(v4i*)(dst + (size_t)tid * 16) = qw;
}

// ---------------------------------------------------------------------------
// int8 GEMM — r7/r19 VERBATIM (session optimum: gemm ~130 µs, MfmaUtil
// ~49-52%, bank conflicts 0, VGPR 120). 256x256 tile, 512 threads = 8
// waves (2M x 4N), per-wave 128x64 of 16x16x64 MFMAs; 4-buffer LDS ring
// (128 KiB); register-double-buffered fragments; 4 groups/tile {3 ds_read
// + 1 global_load_lds + 8 MFMA}; static role split by SIMD sibling;
// setprio on MFMA clusters; counted vmcnt(4) + 1 barrier/tile.
// CLOSED-BY-MEASUREMENT (r3-r20): schedule variants {bulk 52% / T5 52% /
// role-split 52% / unfenced 43% / 8-phase 42% / 2-blk-CU 42%}; 128x128
// wave tiles spill (r10: (256,2) cap; r12: v0-v255 cap); AGPR inline-asm
// MFMA miscompiles deterministically (r13/r14); B-LDS-bypass loses on
// vmem path (r8 gather, r9 L3 bandwidth); 32x32x32 shape re-introduces
// 4-way LDS bank conflicts (r20: 1.28e7, -12 µs). The LDS-port (~1400
// cyc/tile) vs MFMA (~1306 cyc/tile) partial serialization is the
// structural bound of this family at HIP source level.
// ---------------------------------------------------------------------------
__global__ __launch_bounds__(512, 2) void gemm_i8(const int8_t* __restrict__ Aq,
                                                  const int8_t* __restrict__ Bq,
                                                  const float* __restrict__ a_scale,
                                                  const float* __restrict__ w_scale,
                                                  float* __restrict__ out) {
    extern __shared__ __align__(16) int8_t smem[];  // 4 x (A 16K | B 16K)

    const int K = 4096;
    const int bid = blockIdx.x;
    const int wg  = (bid & 7) * 64 + (bid >> 3);  // bijective: 512 = 8 x 64
    const int n0 = (wg & 15) * 256;
    const int m0 = (wg >> 4) * 256;

    const int tid  = threadIdx.x;
    const int lane = tid & 63;
    const int wid  = tid >> 6;
    const int wm   = wid >> 2;
    const int wn   = wid & 3;

    // fragment read offsets (64-B rows, 16-B-chunk XOR swizzle)
    const int rsel  = lane & 15;
    const int kswz  = ((lane >> 4) << 4) ^ (((rsel >> 1) & 3) << 4);
    const int abase = (wm * 128 + rsel) * 64 + kswz;
    const int bbase = 16384 + (wn * 64 + rsel) * 64 + kswz;

    // staging: 512 thr x 16 B = 128 rows/issue; pre-swizzled global source
    const int strow = tid >> 2;
    const int stswz = ((strow >> 1) & 3) << 4;
    const int stcol = ((tid & 3) << 4) ^ stswz;
    const int8_t* gA = Aq + (size_t)(m0 + strow) * K + stcol;
    const int8_t* gB = Bq + (size_t)(n0 + strow) * K + stcol;
    const size_t rstep = (size_t)128 * K;
    const int ldsst = wid * 1024;  // + lane*16 by HW

    v4i acc[8][4] = {};
    v4i aFa[8], aFb[8], bFa[4], bFb[4];

#define STAGE(buf, kt) do {                                                          \
    int8_t* _d = smem + (buf) * 32768;                                               \
    const int8_t* _a = gA + (size_t)(kt) * 64;                                       \
    const int8_t* _b = gB + (size_t)(kt) * 64;                                       \
    __builtin_amdgcn_global_load_lds(AS1C(_a),         AS3(_d + ldsst),         16, 0, 0); \
    __builtin_amdgcn_global_load_lds(AS1C(_a + rstep), AS3(_d + 8192  + ldsst), 16, 0, 0); \
    __builtin_amdgcn_global_load_lds(AS1C(_b),         AS3(_d + 16384 + ldsst), 16, 0, 0); \
    __builtin_amdgcn_global_load_lds(AS1C(_b + rstep), AS3(_d + 24576 + ldsst), 16, 0, 0); \
  } while (0)

#define READS(g, NA, NB, gsrc, goff) do {                                            \
    NA[2*(g)]     = *(const v4i*)(bufN + abase + (2*(g))     * 1024);                \
    NA[2*(g) + 1] = *(const v4i*)(bufN + abase + (2*(g) + 1) * 1024);                \
    NB[(g)]       = *(const v4i*)(bufN + bbase + (g) * 1024);                        \
    __builtin_amdgcn_global_load_lds(AS1C(gsrc), AS3(pD + (goff) + ldsst), 16, 0, 0);\
  } while (0)

#define MFMAS(g, CA, CB) do {                                                        \
    __builtin_amdgcn_s_setprio(1);                                                   \
    _Pragma("unroll")                                                                \
    for (int nt = 0; nt < 4; ++nt) {                                                 \
        acc[2*(g)][nt] = __builtin_amdgcn_mfma_i32_16x16x64_i8(                      \
            CA[2*(g)], CB[nt], acc[2*(g)][nt], 0, 0, 0);                             \
        acc[2*(g)+1][nt] = __builtin_amdgcn_mfma_i32_16x16x64_i8(                    \
            CA[2*(g)+1], CB[nt], acc[2*(g)+1][nt], 0, 0, 0);                         \
    }                                                                                \
    __builtin_amdgcn_s_setprio(0);                                                   \
  } while (0)

    // lead role: reads feed the LDS port while the sibling's MFMAs run
#define GROUP_RW(g, CA, CB, NA, NB, gsrc, goff)  do {                                \
    READS(g, NA, NB, gsrc, goff);                                                    \
    __builtin_amdgcn_sched_barrier(0);                                               \
    MFMAS(g, CA, CB);                                                                \
    __builtin_amdgcn_sched_barrier(0);                                               \
  } while (0)

    // lag role: MFMA first (consumes last-tile registers), reads after
#define GROUP_WR(g, CA, CB, NA, NB, gsrc, goff)  do {                                \
    MFMAS(g, CA, CB);                                                                \
    __builtin_amdgcn_sched_barrier(0);                                               \
    READS(g, NA, NB, gsrc, goff);                                                    \
    __builtin_amdgcn_sched_barrier(0);                                               \
  } while (0)

#define KSTEP(G, u, CA, CB, NA, NB, kt4) do {                                        \
    const int kt  = (kt4) + (u);                                                     \
    const int8_t* bufN = smem + (((u) + 1) & 3) * 32768;                             \
    int8_t* pD = smem + (((u) + 3) & 3) * 32768;                                     \
    const int ktp = (kt + 3 < 64) ? (kt + 3) : 63;                                   \
    const int8_t* _a = gA + (size_t)ktp * 64;                                        \
    const int8_t* _b = gB + (size_t)ktp * 64;                                        \
    asm volatile("s_waitcnt vmcnt(4)" ::: "memory");                                 \
    __builtin_amdgcn_s_barrier();                                                    \
    __builtin_amdgcn_sched_barrier(0);                                               \
    G(0, CA, CB, NA, NB, _a,         0);                                             \
    G(1, CA, CB, NA, NB, _a + rstep, 8192);                                          \
    G(2, CA, CB, NA, NB, _b,         16384);                                         \
    G(3, CA, CB, NA, NB, _b + rstep, 24576);                                         \
  } while (0)

    // ---- prologue: stage tiles 0..2; retire tile 0; load its fragments
    STAGE(0, 0); STAGE(1, 1); STAGE(2, 2);
    asm volatile("s_waitcnt vmcnt(8)" ::: "memory");
    __builtin_amdgcn_s_barrier();
#pragma unroll
    for (int mt = 0; mt < 8; ++mt) aFa[mt] = *(const v4i*)(smem + abase + mt * 1024);
#pragma unroll
    for (int nt = 0; nt < 4; ++nt) bFa[nt] = *(const v4i*)(smem + bbase + nt * 1024);

    if (wid < 4) {  // lead waves: one per SIMD (wid%4 = SIMD id)
        for (int kt4 = 0; kt4 < 64; kt4 += 4) {
            KSTEP(GROUP_RW, 0, aFa, bFa, aFb, bFb, kt4);
            KSTEP(GROUP_RW, 1, aFb, bFb, aFa, bFa, kt4);
            KSTEP(GROUP_RW, 2, aFa, bFa, aFb, bFb, kt4);
            KSTEP(GROUP_RW, 3, aFb, bFb, aFa, bFa, kt4);
        }
    } else {        // lag waves: the SIMD siblings, anti-phased by construction
        for (int kt4 = 0; kt4 < 64; kt4 += 4) {
            KSTEP(GROUP_WR, 0, aFa, bFa, aFb, bFb, kt4);
            KSTEP(GROUP_WR, 1, aFb, bFb, aFa, bFa, kt4);
            KSTEP(GROUP_WR, 2, aFa, bFa, aFb, bFb, kt4);
            KSTEP(GROUP_WR, 3, aFb, bFb, aFa, bFa, kt4);
        }
    }

    // epilogue: C/D layout col = lane&15 (N), row = (lane>>4)*4 + reg (M)
    const int r0  = (lane >> 4) << 2;
    const int col = lane & 15;
#pragma unroll
    for (int mt = 0; mt < 8; ++mt) {
        const int tbase = m0 + wm * 128 + mt * 16 + r0;
        float as[4];
#pragma unroll
        for (int r = 0; r < 4; ++r) as[r] = a_scale[tbase + r];
#pragma unroll
        for (int nt = 0; nt < 4; ++nt) {
            const int o = n0 + wn * 64 + nt * 16 + col;
            const float wsc = w_scale[o];
#pragma unroll
            for (int r = 0; r < 4; ++r) {
                float v = (float)acc[mt][nt][r] * as[r] * wsc;
                out[(size_t)(tbase + r) * 4096 + o] = __half2float(__float2half_rn(v));
            }
        }
    }
#undef KSTEP
#undef GROUP_RW
#undef GROUP_WR
#undef MFMAS
#undef READS
#undef STAGE
}

extern "C" void kernel_launch(void* const* d_in, const int* in_sizes, int n_in,
                              void* d_out, int out_size, void* d_ws, size_t ws_size,
                              hipStream_t stream) {
    const float* input_act = (const float*)d_in[0];  // [4,2048,4096] = [8192,4096]
    const float* weight    = (const float*)d_in[1];  // [4096,4096]
    float* out = (float*)d_out;

    const int K = 4096, O = 4096, T = 8192;

    int8_t* x_q = (int8_t*)d_ws;
    int8_t* w_q = x_q + (size_t)T * K;
    float* a_scale = (float*)(w_q + (size_t)O * K);
    float* w_scale = a_scale + T;

    static bool attr_done = false;
    if (!attr_done) {
        hipFuncSetAttribute(reinterpret_cast<const void*>(gemm_i8),
                            hipFuncAttributeMaxDynamicSharedMemorySize, 131072);
        attr_done = true;
    }

    quant_fused<<<T + O, 256, 0, stream>>>(input_act, weight, x_q, w_q,
                                           a_scale, w_scale);

    dim3 grid(512);  // (8192/256) x (4096/256), XCD-swizzled in-kernel
    gemm_i8<<<grid, 512, 131072, stream>>>(x_q, w_q, a_scale, w_scale, out);
}